// Round 11
// baseline (396.421 us; speedup 1.0000x reference)
//
#include <hip/hip_runtime.h>

typedef _Float16 half8 __attribute__((ext_vector_type(8)));
typedef __attribute__((ext_vector_type(4))) float f32x4;

__device__ __forceinline__ unsigned short f2h(float f) {
    _Float16 h = (_Float16)f;
    return *(unsigned short*)&h;
}
__device__ __forceinline__ float h2f(unsigned short u) {
    _Float16 h = *(_Float16*)&u;
    return (float)h;
}

// ---------- merged prep: x->f16, W1/W2 images, hist zero ----------

__device__ __forceinline__ void wprep_body(
    const float* __restrict__ W, const float* __restrict__ root,
    unsigned short* __restrict__ wb, int dout, int idx)
{
    int c = idx / (64 * dout);
    int rme = idx % (64 * dout);
    int kk = rme / dout;
    int j = rme % dout;
    float f = (c == 0) ? root[kk * dout + j]
                       : W[(size_t)(c - 1) * 64 * dout + kk * dout + j];
    wb[(size_t)c * dout * 72 + (size_t)j * 72 + kk] = f2h(f);
}

__global__ __launch_bounds__(256) void prep_kernel(
    const float* __restrict__ x, unsigned short* __restrict__ xh, int n8,
    const float* __restrict__ W1, const float* __restrict__ root1,
    unsigned short* __restrict__ wb1,
    const float* __restrict__ W2, const float* __restrict__ root2,
    unsigned short* __restrict__ wb2,
    int* __restrict__ hist, int nhist4)
{
    int id = blockIdx.x * 256 + threadIdx.x;
    if (id < n8) {                       // x -> f16, 8 elems/thread
        const f32x4* p = (const f32x4*)(x + (size_t)id * 8);
        f32x4 u = p[0], v = p[1];
        half8 o;
#pragma unroll
        for (int j = 0; j < 4; ++j) {
            o[j] = (_Float16)u[j];
            o[j + 4] = (_Float16)v[j];
        }
        *(half8*)(xh + (size_t)id * 8) = o;
        return;
    }
    id -= n8;
    if (id < 9 * 64 * 64) { wprep_body(W1, root1, wb1, 64, id); return; }
    id -= 9 * 64 * 64;
    if (id < 9 * 64 * 32) { wprep_body(W2, root2, wb2, 32, id); return; }
    id -= 9 * 64 * 32;
    if (id < nhist4) ((int4*)hist)[id] = make_int4(0, 0, 0, 0);
}

// ---------- preprocessing: counting sort by key = dst*8 + rel ----------

__global__ __launch_bounds__(256) void hist8_kernel(
    const int* __restrict__ dst, const int* __restrict__ et,
    int* __restrict__ hist, int E)
{
    int e = blockIdx.x * 256 + threadIdx.x;
    if (e < E) atomicAdd(&hist[dst[e] * 8 + et[e]], 1);
}

#define SCAN_TILE 4096
__global__ __launch_bounds__(1024) void scanA_kernel(
    const int* __restrict__ hist, int* __restrict__ bstart,
    int* __restrict__ partial, int nkeys)
{
    __shared__ int wsum[16];
    const int t = threadIdx.x;
    const int lane = t & 63, w = t >> 6;
    const int base = blockIdx.x * SCAN_TILE + t * 4;
    int v[4];
    int s = 0;
#pragma unroll
    for (int i = 0; i < 4; ++i) {
        v[i] = (base + i < nkeys) ? hist[base + i] : 0;
        s += v[i];
    }
    int inc = s;
#pragma unroll
    for (int off = 1; off < 64; off <<= 1) {
        int u = __shfl_up(inc, off);
        if (lane >= off) inc += u;
    }
    if (lane == 63) wsum[w] = inc;
    __syncthreads();
    if (w == 0 && lane < 16) {
        int ws = wsum[lane];
        int winc = ws;
#pragma unroll
        for (int off = 1; off < 16; off <<= 1) {
            int u = __shfl_up(winc, off);
            if (lane >= off) winc += u;
        }
        wsum[lane] = winc - ws;   // exclusive
    }
    __syncthreads();
    int run = wsum[w] + (inc - s);
#pragma unroll
    for (int i = 0; i < 4; ++i) {
        if (base + i < nkeys) bstart[base + i] = run;
        run += v[i];
    }
    if (t == 1023) partial[blockIdx.x] = run;   // block total
}

__global__ __launch_bounds__(64) void scanB_kernel(
    const int* __restrict__ partial, int* __restrict__ pscan,
    int* __restrict__ bstart_end, int nblk)
{
    const int lane = threadIdx.x;
    int running = 0;
    for (int b = 0; b < nblk; b += 64) {
        int i = b + lane;
        int o = (i < nblk) ? partial[i] : 0;
        int v = o;
#pragma unroll
        for (int off = 1; off < 64; off <<= 1) {
            int u = __shfl_up(v, off);
            if (lane >= off) v += u;
        }
        if (i < nblk) pscan[i] = running + v - o;
        running += __shfl(v, 63);
    }
    if (lane == 0) *bstart_end = running;   // == E
}

// scatter: pos = bstart[key] + pscan + (atomicSub(hist)-1).
// Within-segment order is arbitrary (sum is order-independent); hist is dead
// after scanA, so it doubles as the cursor -- no rank array at all.
__global__ __launch_bounds__(256) void scatter_kernel(
    const int* __restrict__ src, const int* __restrict__ dst,
    const int* __restrict__ et, int* __restrict__ hist,
    const int* __restrict__ bstart, const int* __restrict__ pscan,
    unsigned* __restrict__ srt, int E)
{
    int e = blockIdx.x * 256 + threadIdx.x;
    if (e < E) {
        int key = dst[e] * 8 + et[e];
        int r = atomicSub(&hist[key], 1) - 1;
        srt[bstart[key] + pscan[key >> 12] + r] = (unsigned)src[e];
    }
}

// ---------- fused layer: aggregate means into LDS A-tile, then MFMA dense ----------
// Block = 256 threads (4 waves) = 16 nodes; wave w owns 4 nodes (32 segments).
// ROUND-10 BUG FIX: both register-buffer pipelines (arrays AND named scalars)
// were spilled to scratch by the allocator (VGPR_Count=32 both times; 31.5ms
// first-dispatch scratch-alloc stall), and the spill stores forced per-load
// waitcnts -> serial gathers. Now the pipeline buffer is LDS, filled by
// __builtin_amdgcn_global_load_lds (no destination VGPR -> nothing to spill;
// vmcnt-counted; modeled as a memory op so it cannot cross the asm fences).
// One DMA per EDGE PAIR: lanes 0-31 fetch row q_lo, lanes 32-63 row q_hi,
// 4B/lane -> 256B slot. Batch = 8 pairs = 16 edges, ping-pong 2 buffers/wave,
// steady s_waitcnt vmcnt(8) (never 0 mid-chunk) + sched_barrier(0).

template <int DOUT, int RELU, int OUTH>
__global__ __launch_bounds__(256, 4) void fused_kernel(
    const unsigned short* __restrict__ tab,   // (N,64) f16 gather/self table
    const unsigned* __restrict__ srt,         // src per edge (sorted by dst*8+rel)
    const int* __restrict__ bstart,           // (N*8+1) LOCAL scan (pre-pscan)
    const int* __restrict__ pscan,            // per-4096-tile offsets
    const unsigned short* __restrict__ wb,    // (9, DOUT, 72) f16
    const float* __restrict__ bias,
    float* __restrict__ outf,                 // fp32 out (OUTH=0)
    unsigned short* __restrict__ outh,        // f16 out, stride 64 (OUTH=1)
    int n_nodes, int Etot)
{
    __shared__ __align__(16) unsigned short Atile[16 * 600];   // 19.2 KB
    __shared__ __align__(16) unsigned char SBUF[4][2][2048];   // 16 KB staging

    const int t = threadIdx.x;
    const int w = t >> 6, lane = t & 63;
    const int quad = lane >> 4, l16 = lane & 15;
    const int nbt = blockIdx.x * 16;
    const int nb4 = nbt + w * 4;
    const int KEYS = n_nodes * 8;

    // ---- aggregation phase (wave-private rows + wave-private staging) ----
    {
        const int nb0 = nb4 * 8;                          // 32 keys for this wave
        int idx = nb0 + lane; if (idx > KEYS) idx = KEYS;
        int lv;
        if (idx < KEYS) lv = bstart[idx] + pscan[idx >> 12];
        else            lv = Etot;
        const int E0 = __builtin_amdgcn_readlane(lv, 0);
        const int E1 = __builtin_amdgcn_readlane(lv, 32);

        // per-segment reciprocal counts (lanes 0..31 valid)
        int cntv = __shfl_down(lv, 1) - lv;
        float rsc = 1.0f / fmaxf((float)cntv, 1.0f);

        // self rows (chunk 0)
#pragma unroll
        for (int i = 0; i < 4; ++i) {
            int node = nb4 + i;
            unsigned short v = 0;
            if (node < n_nodes) v = tab[(size_t)node * 64 + lane];
            Atile[(w * 4 + i) * 600 + lane] = v;
        }

        float acc0 = 0.f, acc1 = 0.f;
        int R = 0;                                        // segment index 0..31
        int bnext = __builtin_amdgcn_readlane(lv, 1);

        auto flushes = [&](int eabs) {
            while (R < 32 && eabs == bnext) {
                float sc = __uint_as_float(
                    __builtin_amdgcn_readlane(__float_as_uint(rsc), R));
                Atile[(w * 4 + (R >> 3)) * 600 + 64 + (R & 7) * 64 + lane] =
                    f2h((acc0 + acc1) * sc);
                acc0 = 0.f; acc1 = 0.f;
                ++R;
                bnext = (R < 31) ? __builtin_amdgcn_readlane(lv, R + 1) : E1;
            }
        };

        const char* tabc = (const char*)tab;
        const unsigned loff = (unsigned)(lane & 31) << 2;   // byte off in row
        unsigned rec = 0;

        // 8 pair-DMAs: pair s covers edges (kb+2s, kb+2s+1); lanes 0-31 take
        // the low edge's row, lanes 32-63 the high edge's row, 4B per lane.
        auto issue8 = [&](int buf, int kb) {
#pragma unroll
            for (int s = 0; s < 8; ++s) {
                int qlo = __builtin_amdgcn_readlane((int)rec, kb + 2 * s);
                int qhi = __builtin_amdgcn_readlane((int)rec, kb + 2 * s + 1);
                const char* rl = tabc + ((size_t)(unsigned)qlo << 7);
                const char* rh = tabc + ((size_t)(unsigned)qhi << 7);
                const char* gp = ((lane < 32) ? rl : rh) + loff;
                __builtin_amdgcn_global_load_lds(
                    (const __attribute__((address_space(1))) unsigned*)gp,
                    (__attribute__((address_space(3))) unsigned*)
                        &SBUF[w][buf][s * 256],
                    4, 0, 0);
            }
        };

        int base = E0;
        if (base < E1 && lane < E1 - base) rec = srt[base + lane];
        while (base < E1) {
            const int blen = min(64, E1 - base);
            const int nbase = base + 64;
            unsigned recn = 0;
            if (nbase < E1) {
                // asm prefetch of next srt chunk: uniform SGPR base + per-lane
                // clamped VGPR byte offset. Oldest op -> drained by any wait.
                int ei = nbase + lane;
                if (ei > E1 - 1) ei = E1 - 1;
                unsigned eoff = (unsigned)ei << 2;
                asm volatile("global_load_dword %0, %1, %2"
                             : "=v"(recn) : "v"(eoff), "s"(srt));
            }

            int buf = 0;
            issue8(0, 0);                            // batch 0 -> buffer 0
            for (int B = 0; B < blen; B += 16) {
                if (B + 16 < blen) {
                    issue8(buf ^ 1, B + 16);         // next batch in flight
                    asm volatile("s_waitcnt vmcnt(8)" ::: "memory");
                } else {
                    asm volatile("s_waitcnt vmcnt(0)" ::: "memory");
                }
                __builtin_amdgcn_sched_barrier(0);
                const unsigned short* sb =
                    (const unsigned short*)&SBUF[w][buf][0];
#pragma unroll
                for (int s = 0; s < 8; ++s) {
                    const int e = B + 2 * s;
                    float vlo = h2f(sb[s * 128 + lane]);
                    float vhi = h2f(sb[s * 128 + 64 + lane]);
                    if (e < blen)     { flushes(base + e);     acc0 += vlo; }
                    if (e + 1 < blen) { flushes(base + e + 1); acc1 += vhi; }
                }
                buf ^= 1;
            }
            base = nbase;
            // final wait in the loop above was vmcnt(0)+SB: recn complete and
            // this copy cannot be scheduled above that fence.
            rec = recn;
        }
        flushes(E1);
        while (R < 32) {   // drain trailing empty segments
            float sc = __uint_as_float(
                __builtin_amdgcn_readlane(__float_as_uint(rsc), R));
            Atile[(w * 4 + (R >> 3)) * 600 + 64 + (R & 7) * 64 + lane] =
                f2h((acc0 + acc1) * sc);
            acc0 = 0.f; acc1 = 0.f;
            ++R;
        }
    }

    __syncthreads();

    // ---- MFMA dense phase: wave w = j-tile w ----
    constexpr int JPW = DOUT / 16;       // 4 (DOUT=64) or 2 (DOUT=32)
    if (JPW == 2 && w >= 2) return;      // DOUT=32: waves 2,3 done (after barrier)

    const int j = w * 16 + l16;
    f32x4 d = {0.f, 0.f, 0.f, 0.f};
    const unsigned short* arow = &Atile[l16 * 600];
#pragma unroll
    for (int c = 0; c < 9; ++c) {
        half8 a0 = *(const half8*)(arow + c * 64 + quad * 8);
        half8 a1 = *(const half8*)(arow + c * 64 + 32 + quad * 8);
        half8 b0 = *(const half8*)&wb[c * DOUT * 72 + j * 72 + quad * 8];
        half8 b1 = *(const half8*)&wb[c * DOUT * 72 + j * 72 + 32 + quad * 8];
        d = __builtin_amdgcn_mfma_f32_16x16x32_f16(a0, b0, d, 0, 0, 0);
        d = __builtin_amdgcn_mfma_f32_16x16x32_f16(a1, b1, d, 0, 0, 0);
    }

    // epilogue: C/D layout col = l16 (j), row = quad*4 + reg (node within tile)
    const float bj = bias[j];
#pragma unroll
    for (int r = 0; r < 4; ++r) {
        const int node = nbt + quad * 4 + r;
        if (node < n_nodes) {
            float v = d[r] + bj;
            if (RELU) v = fmaxf(v, 0.0f);
            if (OUTH) outh[(size_t)node * 64 + j] = f2h(v);
            else      outf[(size_t)node * DOUT + j] = v;
        }
    }
}

extern "C" void kernel_launch(void* const* d_in, const int* in_sizes, int n_in,
                              void* d_out, int out_size, void* d_ws, size_t ws_size,
                              hipStream_t stream) {
    const float* x     = (const float*)d_in[0];
    const float* W1    = (const float*)d_in[1];
    const float* root1 = (const float*)d_in[2];
    const float* b1    = (const float*)d_in[3];
    const float* W2    = (const float*)d_in[4];
    const float* root2 = (const float*)d_in[5];
    const float* b2    = (const float*)d_in[6];
    const int*   src   = (const int*)d_in[7];
    const int*   dst   = (const int*)d_in[8];
    const int*   et    = (const int*)d_in[9];

    const int N = in_sizes[0] / 64;
    const int E = in_sizes[7];
    const int KEYS = N * 8;

    char* p = (char*)d_ws;
    auto alloc = [&](size_t bytes) {
        char* r = p;
        p += (bytes + 15) & ~(size_t)15;
        return r;
    };
    unsigned* srt       = (unsigned*)alloc((size_t)E * 4);
    int* hist           = (int*)alloc((size_t)KEYS * 4);
    int* bstart         = (int*)alloc((size_t)(KEYS + 1) * 4);
    int* partial        = (int*)alloc(256 * 4);
    int* pscan          = (int*)alloc(256 * 4);
    unsigned short* wb1 = (unsigned short*)alloc((size_t)9 * 64 * 72 * 2);
    unsigned short* wb2 = (unsigned short*)alloc((size_t)9 * 32 * 72 * 2);
    unsigned short* xh  = (unsigned short*)alloc((size_t)N * 64 * 2);
    unsigned short* h   = (unsigned short*)alloc((size_t)N * 64 * 2);

    const int n8 = N * 8;                 // xprep items
    const int nhist4 = KEYS / 4;          // hist zero items (int4)
    const int prep_items = n8 + 9 * 64 * 64 + 9 * 64 * 32 + nhist4;
    prep_kernel<<<(prep_items + 255) / 256, 256, 0, stream>>>(
        x, xh, n8, W1, root1, wb1, W2, root2, wb2, hist, nhist4);

    hist8_kernel<<<(E + 255) / 256, 256, 0, stream>>>(dst, et, hist, E);
    const int nscan = (KEYS + SCAN_TILE - 1) / SCAN_TILE;
    scanA_kernel<<<nscan, 1024, 0, stream>>>(hist, bstart, partial, KEYS);
    scanB_kernel<<<1, 64, 0, stream>>>(partial, pscan, bstart + KEYS, nscan);
    scatter_kernel<<<(E + 255) / 256, 256, 0, stream>>>(
        src, dst, et, hist, bstart, pscan, srt, E);

    // layer 1: fused agg+dense over xh -> h (relu, f16)
    fused_kernel<64, 1, 1><<<(N + 15) / 16, 256, 0, stream>>>(
        xh, srt, bstart, pscan, wb1, b1, nullptr, h, N, E);
    // layer 2: fused agg+dense over h -> out (fp32)
    fused_kernel<32, 0, 0><<<(N + 15) / 16, 256, 0, stream>>>(
        h, srt, bstart, pscan, wb2, b2, (float*)d_out, nullptr, N, E);
}

// Round 12
// 340.550 us; speedup vs baseline: 1.1641x; 1.1641x over previous
//
#include <hip/hip_runtime.h>

typedef _Float16 half8 __attribute__((ext_vector_type(8)));
typedef __attribute__((ext_vector_type(4))) float f32x4;

__device__ __forceinline__ unsigned short f2h(float f) {
    _Float16 h = (_Float16)f;
    return *(unsigned short*)&h;
}
__device__ __forceinline__ float h2f(unsigned short u) {
    _Float16 h = *(_Float16*)&u;
    return (float)h;
}

// ---------- merged prep: x->f16, W1/W2 images, hist zero ----------

__device__ __forceinline__ void wprep_body(
    const float* __restrict__ W, const float* __restrict__ root,
    unsigned short* __restrict__ wb, int dout, int idx)
{
    int c = idx / (64 * dout);
    int rme = idx % (64 * dout);
    int kk = rme / dout;
    int j = rme % dout;
    float f = (c == 0) ? root[kk * dout + j]
                       : W[(size_t)(c - 1) * 64 * dout + kk * dout + j];
    wb[(size_t)c * dout * 72 + (size_t)j * 72 + kk] = f2h(f);
}

__global__ __launch_bounds__(256) void prep_kernel(
    const float* __restrict__ x, unsigned short* __restrict__ xh, int n8,
    const float* __restrict__ W1, const float* __restrict__ root1,
    unsigned short* __restrict__ wb1,
    const float* __restrict__ W2, const float* __restrict__ root2,
    unsigned short* __restrict__ wb2,
    int* __restrict__ hist, int nhist4)
{
    int id = blockIdx.x * 256 + threadIdx.x;
    if (id < n8) {                       // x -> f16, 8 elems/thread
        const f32x4* p = (const f32x4*)(x + (size_t)id * 8);
        f32x4 u = p[0], v = p[1];
        half8 o;
#pragma unroll
        for (int j = 0; j < 4; ++j) {
            o[j] = (_Float16)u[j];
            o[j + 4] = (_Float16)v[j];
        }
        *(half8*)(xh + (size_t)id * 8) = o;
        return;
    }
    id -= n8;
    if (id < 9 * 64 * 64) { wprep_body(W1, root1, wb1, 64, id); return; }
    id -= 9 * 64 * 64;
    if (id < 9 * 64 * 32) { wprep_body(W2, root2, wb2, 32, id); return; }
    id -= 9 * 64 * 32;
    if (id < nhist4) ((int4*)hist)[id] = make_int4(0, 0, 0, 0);
}

// ---------- preprocessing: counting sort by key = dst*8 + rel ----------

__global__ __launch_bounds__(256) void hist8_kernel(
    const int* __restrict__ dst, const int* __restrict__ et,
    int* __restrict__ hist, int E)
{
    int e = blockIdx.x * 256 + threadIdx.x;
    if (e < E) atomicAdd(&hist[dst[e] * 8 + et[e]], 1);
}

#define SCAN_TILE 4096
__global__ __launch_bounds__(1024) void scanA_kernel(
    const int* __restrict__ hist, int* __restrict__ bstart,
    int* __restrict__ partial, int nkeys)
{
    __shared__ int wsum[16];
    const int t = threadIdx.x;
    const int lane = t & 63, w = t >> 6;
    const int base = blockIdx.x * SCAN_TILE + t * 4;
    int v[4];
    int s = 0;
#pragma unroll
    for (int i = 0; i < 4; ++i) {
        v[i] = (base + i < nkeys) ? hist[base + i] : 0;
        s += v[i];
    }
    int inc = s;
#pragma unroll
    for (int off = 1; off < 64; off <<= 1) {
        int u = __shfl_up(inc, off);
        if (lane >= off) inc += u;
    }
    if (lane == 63) wsum[w] = inc;
    __syncthreads();
    if (w == 0 && lane < 16) {
        int ws = wsum[lane];
        int winc = ws;
#pragma unroll
        for (int off = 1; off < 16; off <<= 1) {
            int u = __shfl_up(winc, off);
            if (lane >= off) winc += u;
        }
        wsum[lane] = winc - ws;   // exclusive
    }
    __syncthreads();
    int run = wsum[w] + (inc - s);
#pragma unroll
    for (int i = 0; i < 4; ++i) {
        if (base + i < nkeys) bstart[base + i] = run;
        run += v[i];
    }
    if (t == 1023) partial[blockIdx.x] = run;   // block total
}

__global__ __launch_bounds__(64) void scanB_kernel(
    const int* __restrict__ partial, int* __restrict__ pscan,
    int* __restrict__ bstart_end, int nblk)
{
    const int lane = threadIdx.x;
    int running = 0;
    for (int b = 0; b < nblk; b += 64) {
        int i = b + lane;
        int o = (i < nblk) ? partial[i] : 0;
        int v = o;
#pragma unroll
        for (int off = 1; off < 64; off <<= 1) {
            int u = __shfl_up(v, off);
            if (lane >= off) v += u;
        }
        if (i < nblk) pscan[i] = running + v - o;
        running += __shfl(v, 63);
    }
    if (lane == 0) *bstart_end = running;   // == E
}

// scatter: pos = bstart[key] + pscan + (atomicSub(hist)-1).
// Record = src*64 (pre-scaled word index into the f16 table; one v_add in the
// gather loop). Within-segment order arbitrary; hist doubles as cursor.
__global__ __launch_bounds__(256) void scatter_kernel(
    const int* __restrict__ src, const int* __restrict__ dst,
    const int* __restrict__ et, int* __restrict__ hist,
    const int* __restrict__ bstart, const int* __restrict__ pscan,
    unsigned* __restrict__ srt, int E)
{
    int e = blockIdx.x * 256 + threadIdx.x;
    if (e < E) {
        int key = dst[e] * 8 + et[e];
        int r = atomicSub(&hist[key], 1) - 1;
        srt[bstart[key] + pscan[key >> 12] + r] = (unsigned)src[e] << 6;
    }
}

// ---------- fused layer: aggregate means into LDS A-tile, then MFMA dense ----------
// Block = 256 threads (4 waves) = 16 nodes; wave w owns 4 nodes (32 segments).
// ROUND-12 STRUCTURAL REVERT OF THE GATHER LOOP: every scalar/readlane-addressed
// pipeline (r4-r11: HIP regs, asm+arrays, asm+named-scalars, global_load_lds)
// serialized at ~1 HBM latency/edge. The vector-addressed designs (r1/r2:
// __shfl -> VGPR address, plain HIP loads, deep unroll) measurably pipelined
// (3.1-3.3 TB/s, r2 VALUBusy 86%). So: 8-deep __shfl + vector gather, loads
// all issued before the consume chain; compiler inserts descending vmcnt
// waits per use (proven MLP pattern). No asm in the loop.

template <int DOUT, int RELU, int OUTH>
__global__ __launch_bounds__(256, 6) void fused_kernel(
    const unsigned short* __restrict__ tab,   // (N,64) f16 gather/self table
    const unsigned* __restrict__ srt,         // src*64 per edge (sorted)
    const int* __restrict__ bstart,           // (N*8+1) LOCAL scan (pre-pscan)
    const int* __restrict__ pscan,            // per-4096-tile offsets
    const unsigned short* __restrict__ wb,    // (9, DOUT, 72) f16
    const float* __restrict__ bias,
    float* __restrict__ outf,                 // fp32 out (OUTH=0)
    unsigned short* __restrict__ outh,        // f16 out, stride 64 (OUTH=1)
    int n_nodes, int Etot)
{
    __shared__ __align__(16) unsigned short Atile[16 * 600];   // 19.2 KB

    const int t = threadIdx.x;
    const int w = t >> 6, lane = t & 63;
    const int quad = lane >> 4, l16 = lane & 15;
    const int nbt = blockIdx.x * 16;
    const int nb4 = nbt + w * 4;
    const int KEYS = n_nodes * 8;

    // ---- aggregation phase (wave-private rows) ----
    {
        const int nb0 = nb4 * 8;                          // 32 keys for this wave
        int idx = nb0 + lane; if (idx > KEYS) idx = KEYS;
        int lv;
        if (idx < KEYS) lv = bstart[idx] + pscan[idx >> 12];
        else            lv = Etot;
        const int E0 = __builtin_amdgcn_readlane(lv, 0);
        const int E1 = __builtin_amdgcn_readlane(lv, 32);

        // per-segment reciprocal counts (lanes 0..31 valid)
        int cntv = __shfl_down(lv, 1) - lv;
        float rsc = 1.0f / fmaxf((float)cntv, 1.0f);

        // self rows (chunk 0)
#pragma unroll
        for (int i = 0; i < 4; ++i) {
            int node = nb4 + i;
            unsigned short v = 0;
            if (node < n_nodes) v = tab[(size_t)node * 64 + lane];
            Atile[(w * 4 + i) * 600 + lane] = v;
        }

        float acc0 = 0.f, acc1 = 0.f;
        int R = 0;                                        // segment index 0..31
        int bnext = __builtin_amdgcn_readlane(lv, 1);

        auto flushes = [&](int eabs) {
            while (R < 32 && eabs == bnext) {
                float sc = __uint_as_float(
                    __builtin_amdgcn_readlane(__float_as_uint(rsc), R));
                Atile[(w * 4 + (R >> 3)) * 600 + 64 + (R & 7) * 64 + lane] =
                    f2h((acc0 + acc1) * sc);
                acc0 = 0.f; acc1 = 0.f;
                ++R;
                bnext = (R < 31) ? __builtin_amdgcn_readlane(lv, R + 1) : E1;
            }
        };

        int base = E0;
        while (base < E1) {
            const int blen = min(64, E1 - base);
            unsigned rec = 0;
            if (lane < blen) rec = srt[base + lane];
            int k = 0;
            for (; k + 8 <= blen; k += 8) {
                // broadcast 8 edge records (VGPR), then 8 vector gathers --
                // all loads issued before the first consume (MLP = 8)
                unsigned q0 = __shfl(rec, k),     q1 = __shfl(rec, k + 1);
                unsigned q2 = __shfl(rec, k + 2), q3 = __shfl(rec, k + 3);
                unsigned q4 = __shfl(rec, k + 4), q5 = __shfl(rec, k + 5);
                unsigned q6 = __shfl(rec, k + 6), q7 = __shfl(rec, k + 7);
                float v0 = h2f(tab[q0 + lane]), v1 = h2f(tab[q1 + lane]);
                float v2 = h2f(tab[q2 + lane]), v3 = h2f(tab[q3 + lane]);
                float v4 = h2f(tab[q4 + lane]), v5 = h2f(tab[q5 + lane]);
                float v6 = h2f(tab[q6 + lane]), v7 = h2f(tab[q7 + lane]);
                flushes(base + k);     acc0 += v0;
                flushes(base + k + 1); acc1 += v1;
                flushes(base + k + 2); acc0 += v2;
                flushes(base + k + 3); acc1 += v3;
                flushes(base + k + 4); acc0 += v4;
                flushes(base + k + 5); acc1 += v5;
                flushes(base + k + 6); acc0 += v6;
                flushes(base + k + 7); acc1 += v7;
            }
            for (; k < blen; ++k) {
                unsigned q = __shfl(rec, k);
                float v = h2f(tab[q + lane]);
                flushes(base + k);
                acc0 += v;
            }
            base += 64;
        }
        flushes(E1);
        while (R < 32) {   // drain trailing empty segments
            float sc = __uint_as_float(
                __builtin_amdgcn_readlane(__float_as_uint(rsc), R));
            Atile[(w * 4 + (R >> 3)) * 600 + 64 + (R & 7) * 64 + lane] =
                f2h((acc0 + acc1) * sc);
            acc0 = 0.f; acc1 = 0.f;
            ++R;
        }
    }

    __syncthreads();

    // ---- MFMA dense phase: wave w = j-tile w ----
    constexpr int JPW = DOUT / 16;       // 4 (DOUT=64) or 2 (DOUT=32)
    if (JPW == 2 && w >= 2) return;      // DOUT=32: waves 2,3 done (after barrier)

    const int j = w * 16 + l16;
    f32x4 d = {0.f, 0.f, 0.f, 0.f};
    const unsigned short* arow = &Atile[l16 * 600];
#pragma unroll
    for (int c = 0; c < 9; ++c) {
        half8 a0 = *(const half8*)(arow + c * 64 + quad * 8);
        half8 a1 = *(const half8*)(arow + c * 64 + 32 + quad * 8);
        half8 b0 = *(const half8*)&wb[c * DOUT * 72 + j * 72 + quad * 8];
        half8 b1 = *(const half8*)&wb[c * DOUT * 72 + j * 72 + 32 + quad * 8];
        d = __builtin_amdgcn_mfma_f32_16x16x32_f16(a0, b0, d, 0, 0, 0);
        d = __builtin_amdgcn_mfma_f32_16x16x32_f16(a1, b1, d, 0, 0, 0);
    }

    // epilogue: C/D layout col = l16 (j), row = quad*4 + reg (node within tile)
    const float bj = bias[j];
#pragma unroll
    for (int r = 0; r < 4; ++r) {
        const int node = nbt + quad * 4 + r;
        if (node < n_nodes) {
            float v = d[r] + bj;
            if (RELU) v = fmaxf(v, 0.0f);
            if (OUTH) outh[(size_t)node * 64 + j] = f2h(v);
            else      outf[(size_t)node * DOUT + j] = v;
        }
    }
}

extern "C" void kernel_launch(void* const* d_in, const int* in_sizes, int n_in,
                              void* d_out, int out_size, void* d_ws, size_t ws_size,
                              hipStream_t stream) {
    const float* x     = (const float*)d_in[0];
    const float* W1    = (const float*)d_in[1];
    const float* root1 = (const float*)d_in[2];
    const float* b1    = (const float*)d_in[3];
    const float* W2    = (const float*)d_in[4];
    const float* root2 = (const float*)d_in[5];
    const float* b2    = (const float*)d_in[6];
    const int*   src   = (const int*)d_in[7];
    const int*   dst   = (const int*)d_in[8];
    const int*   et    = (const int*)d_in[9];

    const int N = in_sizes[0] / 64;
    const int E = in_sizes[7];
    const int KEYS = N * 8;

    char* p = (char*)d_ws;
    auto alloc = [&](size_t bytes) {
        char* r = p;
        p += (bytes + 15) & ~(size_t)15;
        return r;
    };
    unsigned* srt       = (unsigned*)alloc((size_t)E * 4);
    int* hist           = (int*)alloc((size_t)KEYS * 4);
    int* bstart         = (int*)alloc((size_t)(KEYS + 1) * 4);
    int* partial        = (int*)alloc(256 * 4);
    int* pscan          = (int*)alloc(256 * 4);
    unsigned short* wb1 = (unsigned short*)alloc((size_t)9 * 64 * 72 * 2);
    unsigned short* wb2 = (unsigned short*)alloc((size_t)9 * 32 * 72 * 2);
    unsigned short* xh  = (unsigned short*)alloc((size_t)N * 64 * 2);
    unsigned short* h   = (unsigned short*)alloc((size_t)N * 64 * 2);

    const int n8 = N * 8;                 // xprep items
    const int nhist4 = KEYS / 4;          // hist zero items (int4)
    const int prep_items = n8 + 9 * 64 * 64 + 9 * 64 * 32 + nhist4;
    prep_kernel<<<(prep_items + 255) / 256, 256, 0, stream>>>(
        x, xh, n8, W1, root1, wb1, W2, root2, wb2, hist, nhist4);

    hist8_kernel<<<(E + 255) / 256, 256, 0, stream>>>(dst, et, hist, E);
    const int nscan = (KEYS + SCAN_TILE - 1) / SCAN_TILE;
    scanA_kernel<<<nscan, 1024, 0, stream>>>(hist, bstart, partial, KEYS);
    scanB_kernel<<<1, 64, 0, stream>>>(partial, pscan, bstart + KEYS, nscan);
    scatter_kernel<<<(E + 255) / 256, 256, 0, stream>>>(
        src, dst, et, hist, bstart, pscan, srt, E);

    // layer 1: fused agg+dense over xh -> h (relu, f16)
    fused_kernel<64, 1, 1><<<(N + 15) / 16, 256, 0, stream>>>(
        xh, srt, bstart, pscan, wb1, b1, nullptr, h, N, E);
    // layer 2: fused agg+dense over h -> out (fp32)
    fused_kernel<32, 0, 0><<<(N + 15) / 16, 256, 0, stream>>>(
        h, srt, bstart, pscan, wb2, b2, (float*)d_out, nullptr, N, E);
}